// Round 4
// baseline (714.494 us; speedup 1.0000x reference)
//
#include <hip/hip_runtime.h>
#include <hip/hip_fp16.h>

// Problem constants
#define NN 50000              // num nodes
#define EE 300000             // edges per type
#define ETOT (3 * EE)         // 900000
#define HD 64                 // hidden / feature size
#define NKEY (3 * NN)         // (row,etype) keys = 150000
#define SCAN_BLOCKS ((NKEY + 1023) / 1024)   // 147

// H layout: __half2 H[n*64+f] = (channel0, channel1), fp16 storage fp32 math

// ---------------------------------------------------------------------------
// filt[b][l][c][t] = softmax(layerW_b[l][c][:])[t]   -> 24 floats
// ---------------------------------------------------------------------------
__global__ void filt_kernel(const float* __restrict__ lw0,
                            const float* __restrict__ lw1,
                            float* __restrict__ filt) {
    int i = threadIdx.x;
    if (i < 8) {
        int b = i >> 2, l = (i >> 1) & 1, c = i & 1;
        const float* lw = (b == 0 ? lw0 : lw1) + l * 6 + c * 3;
        float a0 = lw[0], a1 = lw[1], a2 = lw[2];
        float m  = fmaxf(a0, fmaxf(a1, a2));
        float e0 = expf(a0 - m), e1 = expf(a1 - m), e2 = expf(a2 - m);
        float s  = e0 + e1 + e2;
        float* o = filt + i * 3;
        o[0] = e0 / s; o[1] = e1 / s; o[2] = e2 / s;
    }
}

// ---------------------------------------------------------------------------
// CSR over key = row*3 + etype : histogram -> 3-phase scan -> scatter
// ---------------------------------------------------------------------------
__global__ void __launch_bounds__(256)
hist_kernel(const int* __restrict__ ei0, const int* __restrict__ ei1,
            const int* __restrict__ ei2, int* __restrict__ cnt3) {
    int t = blockIdx.y;
    const int* ei = (t == 0) ? ei0 : (t == 1) ? ei1 : ei2;
    int e = blockIdx.x * 256 + threadIdx.x;
    if (e < EE) atomicAdd(&cnt3[ei[e] * 3 + t], 1);
}

__global__ void __launch_bounds__(1024)
scanA_kernel(const int* __restrict__ cnt, int* __restrict__ incl,
             int* __restrict__ bsum) {
    __shared__ int wsum[16];
    int tid = threadIdx.x;
    int i = blockIdx.x * 1024 + tid;
    int lane = tid & 63, wv = tid >> 6;
    int v = (i < NKEY) ? cnt[i] : 0;
    int x = v;
#pragma unroll
    for (int d = 1; d < 64; d <<= 1) {
        int y = __shfl_up(x, d);
        if (lane >= d) x += y;
    }
    if (lane == 63) wsum[wv] = x;
    __syncthreads();
    if (wv == 0 && lane < 16) {
        int y = wsum[lane];
#pragma unroll
        for (int d = 1; d < 16; d <<= 1) {
            int z = __shfl_up(y, d);
            if (lane >= d) y += z;
        }
        wsum[lane] = y;
    }
    __syncthreads();
    if (wv > 0) x += wsum[wv - 1];
    if (i < NKEY) incl[i] = x;
    if (tid == 1023) bsum[blockIdx.x] = x;
}

__global__ void __launch_bounds__(256)
scanB_kernel(int* __restrict__ bsum) {
    __shared__ int wsum[4];
    int tid = threadIdx.x, lane = tid & 63, wv = tid >> 6;
    int v = (tid < SCAN_BLOCKS) ? bsum[tid] : 0;
    int x = v;
#pragma unroll
    for (int d = 1; d < 64; d <<= 1) {
        int y = __shfl_up(x, d);
        if (lane >= d) x += y;
    }
    if (lane == 63) wsum[wv] = x;
    __syncthreads();
    if (tid == 0) {
        int s = 0;
        for (int i = 0; i < 4; ++i) { int t = wsum[i]; wsum[i] = s; s += t; }
    }
    __syncthreads();
    x += wsum[wv];
    if (tid < SCAN_BLOCKS) bsum[tid] = x - v;   // exclusive
}

__global__ void __launch_bounds__(1024)
scanC_kernel(const int* __restrict__ cnt, const int* __restrict__ incl,
             const int* __restrict__ bsum, int* __restrict__ rp3,
             int* __restrict__ cursor) {
    int i = blockIdx.x * 1024 + threadIdx.x;
    if (i < NKEY) {
        int total = incl[i] + bsum[blockIdx.x];
        rp3[i + 1] = total;
        cursor[i]  = total - cnt[i];
    }
    if (i == 0) rp3[0] = 0;
}

// meta[pos] = col | (q16(val) << 16);  col < 65536, val in [0,1)
__global__ void __launch_bounds__(256)
scatter_kernel(const int* __restrict__ ei0, const int* __restrict__ ei1,
               const int* __restrict__ ei2,
               const float* __restrict__ ev0, const float* __restrict__ ev1,
               const float* __restrict__ ev2,
               int* __restrict__ cursor, unsigned int* __restrict__ meta) {
    int t = blockIdx.y;
    const int*   ei = (t == 0) ? ei0 : (t == 1) ? ei1 : ei2;
    const float* ev = (t == 0) ? ev0 : (t == 1) ? ev1 : ev2;
    int e = blockIdx.x * 256 + threadIdx.x;
    if (e >= EE) return;
    int row = ei[e];
    int col = ei[EE + e];
    int q   = __float2int_rn(ev[e] * 65535.0f);
    int pos = atomicAdd(&cursor[row * 3 + t], 1);
    meta[pos] = (unsigned int)col | ((unsigned int)q << 16);
}

// ---------------------------------------------------------------------------
// Projection: Hh[n][o] = half2( X@Ws[0], X@Ws[1] )[n][o]
// grid-stride tiles of 32 nodes; each thread: 8 nodes x 1 output x 2 ch
// ---------------------------------------------------------------------------
#define PROJ_TILE 32
__global__ void __launch_bounds__(256)
proj_kernel(const float* __restrict__ Xin, const float* __restrict__ Ws,
            __half2* __restrict__ Hh) {
    __shared__ float Wl[2 * 64 * 64];   // 32 KB
    __shared__ float Xs[PROJ_TILE * 64]; // 8 KB
    int tid = threadIdx.x;
    for (int i = tid; i < 2 * 64 * 64; i += 256) Wl[i] = Ws[i];
    int o = tid & 63, wv = tid >> 6;
    const int ntiles = (NN + PROJ_TILE - 1) / PROJ_TILE;
    for (int tile = blockIdx.x; tile < ntiles; tile += gridDim.x) {
        int n0 = tile * PROJ_TILE;
        __syncthreads();
        for (int i = tid; i < PROJ_TILE * 64; i += 256) {
            int n = n0 + (i >> 6);
            Xs[i] = (n < NN) ? Xin[n * 64 + (i & 63)] : 0.f;
        }
        __syncthreads();
        float a0[8], a1[8];
#pragma unroll
        for (int j = 0; j < 8; ++j) { a0[j] = 0.f; a1[j] = 0.f; }
        for (int f = 0; f < 64; f += 4) {
            float4 xq[8];
#pragma unroll
            for (int j = 0; j < 8; ++j)
                xq[j] = *(const float4*)&Xs[(wv + 4 * j) * 64 + f];
#pragma unroll
            for (int ff = 0; ff < 4; ++ff) {
                float w0 = Wl[(f + ff) * 64 + o];
                float w1 = Wl[4096 + (f + ff) * 64 + o];
#pragma unroll
                for (int j = 0; j < 8; ++j) {
                    float x = (ff == 0) ? xq[j].x : (ff == 1) ? xq[j].y
                             : (ff == 2) ? xq[j].z : xq[j].w;
                    a0[j] += x * w0;
                    a1[j] += x * w1;
                }
            }
        }
#pragma unroll
        for (int j = 0; j < 8; ++j) {
            int n = n0 + wv + 4 * j;
            if (n < NN) Hh[n * HD + o] = __floats2half2_rn(a0[j], a1[j]);
        }
    }
}

// ---------------------------------------------------------------------------
// CSR SpMM-mix: one wave per row, lane = feature; per-etype segments so the
// mix weight is loop-uniform; meta is 4 B; H gathered as half2 (256 B/edge).
// ---------------------------------------------------------------------------
__global__ void __launch_bounds__(256)
spmm_kernel(const __half2* __restrict__ Hin, __half2* __restrict__ Hout,
            const unsigned int* __restrict__ meta, const int* __restrict__ rp3,
            const float* __restrict__ filt /* [2][3] for this pass */) {
    int wid  = threadIdx.x >> 6;
    int lane = threadIdx.x & 63;
    int row  = blockIdx.x * 4 + wid;

    const float inv = 1.0f / 65535.0f;
    float acc0 = 0.f, acc1 = 0.f;
    int b0 = rp3[3 * row], b1 = rp3[3 * row + 1];
    int b2 = rp3[3 * row + 2], b3 = rp3[3 * row + 3];
    int begs[3] = { b0, b1, b2 };
    int ends[3] = { b1, b2, b3 };

#pragma unroll
    for (int t = 0; t < 3; ++t) {
        const float w0 = filt[t] * inv;
        const float w1 = filt[3 + t] * inv;
        for (int j0 = begs[t]; j0 < ends[t]; j0 += 64) {
            int cnt = min(ends[t] - j0, 64);
            unsigned int m = (lane < cnt) ? meta[j0 + lane] : 0u;
            int k = 0;
            for (; k + 4 <= cnt; k += 4) {
                unsigned int m0 = __shfl((int)m, k);
                unsigned int m1 = __shfl((int)m, k + 1);
                unsigned int m2 = __shfl((int)m, k + 2);
                unsigned int m3 = __shfl((int)m, k + 3);
                float2 x0 = __half22float2(Hin[(m0 & 0xffffu) * HD + lane]);
                float2 x1 = __half22float2(Hin[(m1 & 0xffffu) * HD + lane]);
                float2 x2 = __half22float2(Hin[(m2 & 0xffffu) * HD + lane]);
                float2 x3 = __half22float2(Hin[(m3 & 0xffffu) * HD + lane]);
                float q0 = (float)(m0 >> 16), q1 = (float)(m1 >> 16);
                float q2 = (float)(m2 >> 16), q3 = (float)(m3 >> 16);
                acc0 += (q0 * w0) * x0.x; acc1 += (q0 * w1) * x0.y;
                acc0 += (q1 * w0) * x1.x; acc1 += (q1 * w1) * x1.y;
                acc0 += (q2 * w0) * x2.x; acc1 += (q2 * w1) * x2.y;
                acc0 += (q3 * w0) * x3.x; acc1 += (q3 * w1) * x3.y;
            }
            for (; k < cnt; ++k) {
                unsigned int mm = __shfl((int)m, k);
                float2 x = __half22float2(Hin[(mm & 0xffffu) * HD + lane]);
                float qf = (float)(mm >> 16);
                acc0 += (qf * w0) * x.x;
                acc1 += (qf * w1) * x.y;
            }
        }
    }
    Hout[row * HD + lane] = __floats2half2_rn(acc0, acc1);
}

// ---------------------------------------------------------------------------
// Epilogue: Hm = 0.8*relu(0.5*X0+0.5*H) + 0.2*X0 per [c][n][d], then
// out[n] = relu(Hm[n,:128] @ linW + linb).  64-node tiles, 4x4 reg tile.
// ---------------------------------------------------------------------------
#define EPI_TILE 64
#define HS_STRIDE 132   // pad: bank = (4*node + k) & 31, 16B-aligned rows
__global__ void __launch_bounds__(256)
epilogue_kernel(const __half2* __restrict__ X0, const __half2* __restrict__ H,
                const float* __restrict__ linW, const float* __restrict__ linb,
                float* __restrict__ out) {
    __shared__ float Wl[128 * 64];               // 32 KB
    __shared__ float Hs[EPI_TILE * HS_STRIDE];   // 33.8 KB
    int tid = threadIdx.x;
    for (int i = tid; i < 128 * 64; i += 256) Wl[i] = linW[i];
    int oq = tid & 15, nq = tid >> 4;
    float bias[4];
#pragma unroll
    for (int i = 0; i < 4; ++i) bias[i] = linb[oq + 16 * i];
    const int ntiles = (NN + EPI_TILE - 1) / EPI_TILE;
    for (int tile = blockIdx.x; tile < ntiles; tile += gridDim.x) {
        int n0 = tile * EPI_TILE;
        __syncthreads();
        for (int i = tid; i < EPI_TILE * 64; i += 256) {
            int ln = i >> 6, d = i & 63;
            int n = n0 + ln;
            float2 x0 = make_float2(0.f, 0.f), h = make_float2(0.f, 0.f);
            if (n < NN) {
                x0 = __half22float2(X0[n * HD + d]);
                h  = __half22float2(H [n * HD + d]);
            }
            float z0 = fmaxf(0.5f * x0.x + 0.5f * h.x, 0.f);
            float z1 = fmaxf(0.5f * x0.y + 0.5f * h.y, 0.f);
            Hs[ln * HS_STRIDE + d]      = 0.8f * z0 + 0.2f * x0.x;
            Hs[ln * HS_STRIDE + 64 + d] = 0.8f * z1 + 0.2f * x0.y;
        }
        __syncthreads();
        float acc[4][4];
#pragma unroll
        for (int j = 0; j < 4; ++j)
#pragma unroll
            for (int i = 0; i < 4; ++i) acc[j][i] = bias[i];
        for (int k = 0; k < 128; k += 4) {
            float4 hq[4];
#pragma unroll
            for (int j = 0; j < 4; ++j)
                hq[j] = *(const float4*)&Hs[(nq + 16 * j) * HS_STRIDE + k];
#pragma unroll
            for (int kk = 0; kk < 4; ++kk) {
                float w[4];
#pragma unroll
                for (int i = 0; i < 4; ++i) w[i] = Wl[(k + kk) * 64 + oq + 16 * i];
#pragma unroll
                for (int j = 0; j < 4; ++j) {
                    float x = (kk == 0) ? hq[j].x : (kk == 1) ? hq[j].y
                             : (kk == 2) ? hq[j].z : hq[j].w;
#pragma unroll
                    for (int i = 0; i < 4; ++i) acc[j][i] += x * w[i];
                }
            }
        }
#pragma unroll
        for (int j = 0; j < 4; ++j) {
            int n = n0 + nq + 16 * j;
            if (n < NN) {
#pragma unroll
                for (int i = 0; i < 4; ++i)
                    out[n * HD + oq + 16 * i] = fmaxf(acc[j][i], 0.f);
            }
        }
    }
}

// ---------------------------------------------------------------------------
extern "C" void kernel_launch(void* const* d_in, const int* in_sizes, int n_in,
                              void* d_out, int out_size, void* d_ws, size_t ws_size,
                              hipStream_t stream) {
    const float* X     = (const float*)d_in[0];
    const float* ev0   = (const float*)d_in[1];
    const float* ev1   = (const float*)d_in[2];
    const float* ev2   = (const float*)d_in[3];
    const float* Ws0   = (const float*)d_in[4];
    const float* Ws1   = (const float*)d_in[5];
    const float* lw0   = (const float*)d_in[6];
    const float* lw1   = (const float*)d_in[7];
    const float* linW0 = (const float*)d_in[8];
    const float* linb0 = (const float*)d_in[9];
    const float* linW1 = (const float*)d_in[10];
    const float* linb1 = (const float*)d_in[11];
    const int*   ei0   = (const int*)d_in[12];
    const int*   ei1   = (const int*)d_in[13];
    const int*   ei2   = (const int*)d_in[14];
    float* out = (float*)d_out;

    // Workspace (4-byte units):
    // X0h | Ha | Hb (each NN*HD half2) | mid (NN*HD f32) | filt(32) |
    // cnt3(NKEY) | incl(NKEY) | bsum(256) | rp3(NKEY+16) | cursor(NKEY) | meta(ETOT)
    float* ws = (float*)d_ws;
    __half2* X0h = (__half2*)(ws);
    __half2* Ha  = (__half2*)(ws + 1 * NN * HD);
    __half2* Hb  = (__half2*)(ws + 2 * NN * HD);
    float*   mid = ws + 3 * NN * HD;
    float*   filt = ws + 4 * NN * HD;
    int*     cnt3   = (int*)(filt + 32);
    int*     incl   = cnt3 + NKEY;
    int*     bsum   = incl + NKEY;
    int*     rp3    = bsum + 256;
    int*     cursor = rp3 + NKEY + 16;
    unsigned int* meta = (unsigned int*)(cursor + NKEY);

    // ---- filters + (row,etype)-CSR, once per launch ----
    filt_kernel<<<1, 64, 0, stream>>>(lw0, lw1, filt);
    hipMemsetAsync(cnt3, 0, NKEY * sizeof(int), stream);
    dim3 egrid((EE + 255) / 256, 3);
    hist_kernel<<<egrid, 256, 0, stream>>>(ei0, ei1, ei2, cnt3);
    scanA_kernel<<<SCAN_BLOCKS, 1024, 0, stream>>>(cnt3, incl, bsum);
    scanB_kernel<<<1, 256, 0, stream>>>(bsum);
    scanC_kernel<<<SCAN_BLOCKS, 1024, 0, stream>>>(cnt3, incl, bsum, rp3, cursor);
    scatter_kernel<<<egrid, 256, 0, stream>>>(ei0, ei1, ei2, ev0, ev1, ev2,
                                              cursor, meta);

    // ---- FastGTN block 0 ----
    proj_kernel<<<512, 256, 0, stream>>>(X, Ws0, X0h);
    spmm_kernel<<<NN / 4, 256, 0, stream>>>(X0h, Ha, meta, rp3, filt + 0);
    spmm_kernel<<<NN / 4, 256, 0, stream>>>(Ha, Hb, meta, rp3, filt + 6);
    epilogue_kernel<<<512, 256, 0, stream>>>(X0h, Hb, linW0, linb0, mid);

    // ---- FastGTN block 1 ----
    proj_kernel<<<512, 256, 0, stream>>>(mid, Ws1, X0h);
    spmm_kernel<<<NN / 4, 256, 0, stream>>>(X0h, Ha, meta, rp3, filt + 12);
    spmm_kernel<<<NN / 4, 256, 0, stream>>>(Ha, Hb, meta, rp3, filt + 18);
    epilogue_kernel<<<512, 256, 0, stream>>>(X0h, Hb, linW1, linb1, out);
}

// Round 5
// 500.822 us; speedup vs baseline: 1.4266x; 1.4266x over previous
//
#include <hip/hip_runtime.h>
#include <hip/hip_fp16.h>

// Problem constants
#define NN 50000              // num nodes
#define EE 300000             // edges per type
#define ETOT (3 * EE)         // 900000
#define HD 64                 // hidden / feature size
#define NKEY (3 * NN)         // (row,etype) keys = 150000
#define SCAN_BLOCKS ((NKEY + 1023) / 1024)   // 147

// H layout: __half2 H[n*64+f] = (channel0, channel1), fp16 storage fp32 math

// ---------------------------------------------------------------------------
// filt[b][l][c][t] = softmax(layerW_b[l][c][:])[t]   -> 24 floats
// ---------------------------------------------------------------------------
__global__ void filt_kernel(const float* __restrict__ lw0,
                            const float* __restrict__ lw1,
                            float* __restrict__ filt) {
    int i = threadIdx.x;
    if (i < 8) {
        int b = i >> 2, l = (i >> 1) & 1, c = i & 1;
        const float* lw = (b == 0 ? lw0 : lw1) + l * 6 + c * 3;
        float a0 = lw[0], a1 = lw[1], a2 = lw[2];
        float m  = fmaxf(a0, fmaxf(a1, a2));
        float e0 = expf(a0 - m), e1 = expf(a1 - m), e2 = expf(a2 - m);
        float s  = e0 + e1 + e2;
        float* o = filt + i * 3;
        o[0] = e0 / s; o[1] = e1 / s; o[2] = e2 / s;
    }
}

// ---------------------------------------------------------------------------
// CSR over key = row*3 + etype : histogram -> 3-phase scan -> scatter
// ---------------------------------------------------------------------------
__global__ void __launch_bounds__(256)
hist_kernel(const int* __restrict__ ei0, const int* __restrict__ ei1,
            const int* __restrict__ ei2, int* __restrict__ cnt3) {
    int t = blockIdx.y;
    const int* ei = (t == 0) ? ei0 : (t == 1) ? ei1 : ei2;
    int e = blockIdx.x * 256 + threadIdx.x;
    if (e < EE) atomicAdd(&cnt3[ei[e] * 3 + t], 1);
}

__global__ void __launch_bounds__(1024)
scanA_kernel(const int* __restrict__ cnt, int* __restrict__ incl,
             int* __restrict__ bsum) {
    __shared__ int wsum[16];
    int tid = threadIdx.x;
    int i = blockIdx.x * 1024 + tid;
    int lane = tid & 63, wv = tid >> 6;
    int v = (i < NKEY) ? cnt[i] : 0;
    int x = v;
#pragma unroll
    for (int d = 1; d < 64; d <<= 1) {
        int y = __shfl_up(x, d);
        if (lane >= d) x += y;
    }
    if (lane == 63) wsum[wv] = x;
    __syncthreads();
    if (wv == 0 && lane < 16) {
        int y = wsum[lane];
#pragma unroll
        for (int d = 1; d < 16; d <<= 1) {
            int z = __shfl_up(y, d);
            if (lane >= d) y += z;
        }
        wsum[lane] = y;
    }
    __syncthreads();
    if (wv > 0) x += wsum[wv - 1];
    if (i < NKEY) incl[i] = x;
    if (tid == 1023) bsum[blockIdx.x] = x;
}

__global__ void __launch_bounds__(256)
scanB_kernel(int* __restrict__ bsum) {
    __shared__ int wsum[4];
    int tid = threadIdx.x, lane = tid & 63, wv = tid >> 6;
    int v = (tid < SCAN_BLOCKS) ? bsum[tid] : 0;
    int x = v;
#pragma unroll
    for (int d = 1; d < 64; d <<= 1) {
        int y = __shfl_up(x, d);
        if (lane >= d) x += y;
    }
    if (lane == 63) wsum[wv] = x;
    __syncthreads();
    if (tid == 0) {
        int s = 0;
        for (int i = 0; i < 4; ++i) { int t = wsum[i]; wsum[i] = s; s += t; }
    }
    __syncthreads();
    x += wsum[wv];
    if (tid < SCAN_BLOCKS) bsum[tid] = x - v;   // exclusive
}

__global__ void __launch_bounds__(1024)
scanC_kernel(const int* __restrict__ cnt, const int* __restrict__ incl,
             const int* __restrict__ bsum, int* __restrict__ rp3,
             int* __restrict__ cursor) {
    int i = blockIdx.x * 1024 + threadIdx.x;
    if (i < NKEY) {
        int total = incl[i] + bsum[blockIdx.x];
        rp3[i + 1] = total;
        cursor[i]  = total - cnt[i];
    }
    if (i == 0) rp3[0] = 0;
}

// meta[pos] = col | (q16(val) << 16);  col < 65536, val in [0,1)
__global__ void __launch_bounds__(256)
scatter_kernel(const int* __restrict__ ei0, const int* __restrict__ ei1,
               const int* __restrict__ ei2,
               const float* __restrict__ ev0, const float* __restrict__ ev1,
               const float* __restrict__ ev2,
               int* __restrict__ cursor, unsigned int* __restrict__ meta) {
    int t = blockIdx.y;
    const int*   ei = (t == 0) ? ei0 : (t == 1) ? ei1 : ei2;
    const float* ev = (t == 0) ? ev0 : (t == 1) ? ev1 : ev2;
    int e = blockIdx.x * 256 + threadIdx.x;
    if (e >= EE) return;
    int row = ei[e];
    int col = ei[EE + e];
    int q   = __float2int_rn(ev[e] * 65535.0f);
    int pos = atomicAdd(&cursor[row * 3 + t], 1);
    meta[pos] = (unsigned int)col | ((unsigned int)q << 16);
}

// ---------------------------------------------------------------------------
// Projection: Hh[n][o] = half2( X@Ws[0], X@Ws[1] )[n][o]
// Simple low-VGPR form: 4 nodes/tile, thread=(node,output), grid-stride so
// the 32 KB weight stage amortizes over ~12 tiles/block.
// VGPR budget deliberately small — round-4's 8-node register tile spilled
// (VGPR=256, 255 MB scratch writes, 175 µs). Keep this ~32 VGPR.
// ---------------------------------------------------------------------------
#define PROJ_NTILE (NN / 4)   // 12500, exact
__global__ void __launch_bounds__(256)
proj_kernel(const float* __restrict__ Xin, const float* __restrict__ Ws,
            __half2* __restrict__ Hh) {
    __shared__ float Wl[2 * 64 * 64];   // 32 KB
    __shared__ float Xs[4][64];
    int tid = threadIdx.x;
    for (int i = tid; i < 2 * 64 * 64; i += 256) Wl[i] = Ws[i];
    int ln = tid >> 6, o = tid & 63;
    for (int tile = blockIdx.x; tile < PROJ_NTILE; tile += gridDim.x) {
        int n = tile * 4 + ln;
        __syncthreads();                 // Xs reuse (covers first-iter Wl too)
        Xs[ln][o] = Xin[n * 64 + o];
        __syncthreads();
        float a0 = 0.f, a1 = 0.f;
#pragma unroll
        for (int f = 0; f < 64; ++f) {
            float x = Xs[ln][f];
            a0 += x * Wl[f * 64 + o];
            a1 += x * Wl[4096 + f * 64 + o];
        }
        Hh[n * HD + o] = __floats2half2_rn(a0, a1);
    }
}

// ---------------------------------------------------------------------------
// CSR SpMM-mix: one wave per row, lane = feature; per-etype segments so the
// mix weight is loop-uniform; meta is 4 B; H gathered as half2 (256 B/edge).
// ---------------------------------------------------------------------------
__global__ void __launch_bounds__(256)
spmm_kernel(const __half2* __restrict__ Hin, __half2* __restrict__ Hout,
            const unsigned int* __restrict__ meta, const int* __restrict__ rp3,
            const float* __restrict__ filt /* [2][3] for this pass */) {
    int wid  = threadIdx.x >> 6;
    int lane = threadIdx.x & 63;
    int row  = blockIdx.x * 4 + wid;

    const float inv = 1.0f / 65535.0f;
    float acc0 = 0.f, acc1 = 0.f;
    int b0 = rp3[3 * row], b1 = rp3[3 * row + 1];
    int b2 = rp3[3 * row + 2], b3 = rp3[3 * row + 3];
    int begs[3] = { b0, b1, b2 };
    int ends[3] = { b1, b2, b3 };

#pragma unroll
    for (int t = 0; t < 3; ++t) {
        const float w0 = filt[t] * inv;
        const float w1 = filt[3 + t] * inv;
        for (int j0 = begs[t]; j0 < ends[t]; j0 += 64) {
            int cnt = min(ends[t] - j0, 64);
            unsigned int m = (lane < cnt) ? meta[j0 + lane] : 0u;
            int k = 0;
            for (; k + 4 <= cnt; k += 4) {
                unsigned int m0 = __shfl((int)m, k);
                unsigned int m1 = __shfl((int)m, k + 1);
                unsigned int m2 = __shfl((int)m, k + 2);
                unsigned int m3 = __shfl((int)m, k + 3);
                float2 x0 = __half22float2(Hin[(m0 & 0xffffu) * HD + lane]);
                float2 x1 = __half22float2(Hin[(m1 & 0xffffu) * HD + lane]);
                float2 x2 = __half22float2(Hin[(m2 & 0xffffu) * HD + lane]);
                float2 x3 = __half22float2(Hin[(m3 & 0xffffu) * HD + lane]);
                float q0 = (float)(m0 >> 16), q1 = (float)(m1 >> 16);
                float q2 = (float)(m2 >> 16), q3 = (float)(m3 >> 16);
                acc0 += (q0 * w0) * x0.x; acc1 += (q0 * w1) * x0.y;
                acc0 += (q1 * w0) * x1.x; acc1 += (q1 * w1) * x1.y;
                acc0 += (q2 * w0) * x2.x; acc1 += (q2 * w1) * x2.y;
                acc0 += (q3 * w0) * x3.x; acc1 += (q3 * w1) * x3.y;
            }
            for (; k < cnt; ++k) {
                unsigned int mm = __shfl((int)m, k);
                float2 x = __half22float2(Hin[(mm & 0xffffu) * HD + lane]);
                float qf = (float)(mm >> 16);
                acc0 += (qf * w0) * x.x;
                acc1 += (qf * w1) * x.y;
            }
        }
    }
    Hout[row * HD + lane] = __floats2half2_rn(acc0, acc1);
}

// ---------------------------------------------------------------------------
// Epilogue: Hm = 0.8*relu(0.5*X0+0.5*H) + 0.2*X0 per [c][n][d], then
// out[n] = relu(Hm[n,:128] @ linW + linb).  64-node tiles, 4x4 reg tile.
// ---------------------------------------------------------------------------
#define EPI_TILE 64
#define HS_STRIDE 132   // pad: bank = (4*node + k) & 31, 16B-aligned rows
__global__ void __launch_bounds__(256)
epilogue_kernel(const __half2* __restrict__ X0, const __half2* __restrict__ H,
                const float* __restrict__ linW, const float* __restrict__ linb,
                float* __restrict__ out) {
    __shared__ float Wl[128 * 64];               // 32 KB
    __shared__ float Hs[EPI_TILE * HS_STRIDE];   // 33.8 KB
    int tid = threadIdx.x;
    for (int i = tid; i < 128 * 64; i += 256) Wl[i] = linW[i];
    int oq = tid & 15, nq = tid >> 4;
    float bias[4];
#pragma unroll
    for (int i = 0; i < 4; ++i) bias[i] = linb[oq + 16 * i];
    const int ntiles = (NN + EPI_TILE - 1) / EPI_TILE;
    for (int tile = blockIdx.x; tile < ntiles; tile += gridDim.x) {
        int n0 = tile * EPI_TILE;
        __syncthreads();
        for (int i = tid; i < EPI_TILE * 64; i += 256) {
            int ln = i >> 6, d = i & 63;
            int n = n0 + ln;
            float2 x0 = make_float2(0.f, 0.f), h = make_float2(0.f, 0.f);
            if (n < NN) {
                x0 = __half22float2(X0[n * HD + d]);
                h  = __half22float2(H [n * HD + d]);
            }
            float z0 = fmaxf(0.5f * x0.x + 0.5f * h.x, 0.f);
            float z1 = fmaxf(0.5f * x0.y + 0.5f * h.y, 0.f);
            Hs[ln * HS_STRIDE + d]      = 0.8f * z0 + 0.2f * x0.x;
            Hs[ln * HS_STRIDE + 64 + d] = 0.8f * z1 + 0.2f * x0.y;
        }
        __syncthreads();
        float acc[4][4];
#pragma unroll
        for (int j = 0; j < 4; ++j)
#pragma unroll
            for (int i = 0; i < 4; ++i) acc[j][i] = bias[i];
        for (int k = 0; k < 128; k += 4) {
            float4 hq[4];
#pragma unroll
            for (int j = 0; j < 4; ++j)
                hq[j] = *(const float4*)&Hs[(nq + 16 * j) * HS_STRIDE + k];
#pragma unroll
            for (int kk = 0; kk < 4; ++kk) {
                float w[4];
#pragma unroll
                for (int i = 0; i < 4; ++i) w[i] = Wl[(k + kk) * 64 + oq + 16 * i];
#pragma unroll
                for (int j = 0; j < 4; ++j) {
                    float x = (kk == 0) ? hq[j].x : (kk == 1) ? hq[j].y
                             : (kk == 2) ? hq[j].z : hq[j].w;
#pragma unroll
                    for (int i = 0; i < 4; ++i) acc[j][i] += x * w[i];
                }
            }
        }
#pragma unroll
        for (int j = 0; j < 4; ++j) {
            int n = n0 + nq + 16 * j;
            if (n < NN) {
#pragma unroll
                for (int i = 0; i < 4; ++i)
                    out[n * HD + oq + 16 * i] = fmaxf(acc[j][i], 0.f);
            }
        }
    }
}

// ---------------------------------------------------------------------------
extern "C" void kernel_launch(void* const* d_in, const int* in_sizes, int n_in,
                              void* d_out, int out_size, void* d_ws, size_t ws_size,
                              hipStream_t stream) {
    const float* X     = (const float*)d_in[0];
    const float* ev0   = (const float*)d_in[1];
    const float* ev1   = (const float*)d_in[2];
    const float* ev2   = (const float*)d_in[3];
    const float* Ws0   = (const float*)d_in[4];
    const float* Ws1   = (const float*)d_in[5];
    const float* lw0   = (const float*)d_in[6];
    const float* lw1   = (const float*)d_in[7];
    const float* linW0 = (const float*)d_in[8];
    const float* linb0 = (const float*)d_in[9];
    const float* linW1 = (const float*)d_in[10];
    const float* linb1 = (const float*)d_in[11];
    const int*   ei0   = (const int*)d_in[12];
    const int*   ei1   = (const int*)d_in[13];
    const int*   ei2   = (const int*)d_in[14];
    float* out = (float*)d_out;

    // Workspace (4-byte units):
    // X0h | Ha | Hb (each NN*HD half2) | mid (NN*HD f32) | filt(32) |
    // cnt3(NKEY) | incl(NKEY) | bsum(256) | rp3(NKEY+16) | cursor(NKEY) | meta(ETOT)
    float* ws = (float*)d_ws;
    __half2* X0h = (__half2*)(ws);
    __half2* Ha  = (__half2*)(ws + 1 * NN * HD);
    __half2* Hb  = (__half2*)(ws + 2 * NN * HD);
    float*   mid = ws + 3 * NN * HD;
    float*   filt = ws + 4 * NN * HD;
    int*     cnt3   = (int*)(filt + 32);
    int*     incl   = cnt3 + NKEY;
    int*     bsum   = incl + NKEY;
    int*     rp3    = bsum + 256;
    int*     cursor = rp3 + NKEY + 16;
    unsigned int* meta = (unsigned int*)(cursor + NKEY);

    // ---- filters + (row,etype)-CSR, once per launch ----
    filt_kernel<<<1, 64, 0, stream>>>(lw0, lw1, filt);
    hipMemsetAsync(cnt3, 0, NKEY * sizeof(int), stream);
    dim3 egrid((EE + 255) / 256, 3);
    hist_kernel<<<egrid, 256, 0, stream>>>(ei0, ei1, ei2, cnt3);
    scanA_kernel<<<SCAN_BLOCKS, 1024, 0, stream>>>(cnt3, incl, bsum);
    scanB_kernel<<<1, 256, 0, stream>>>(bsum);
    scanC_kernel<<<SCAN_BLOCKS, 1024, 0, stream>>>(cnt3, incl, bsum, rp3, cursor);
    scatter_kernel<<<egrid, 256, 0, stream>>>(ei0, ei1, ei2, ev0, ev1, ev2,
                                              cursor, meta);

    // ---- FastGTN block 0 ----
    proj_kernel<<<1024, 256, 0, stream>>>(X, Ws0, X0h);
    spmm_kernel<<<NN / 4, 256, 0, stream>>>(X0h, Ha, meta, rp3, filt + 0);
    spmm_kernel<<<NN / 4, 256, 0, stream>>>(Ha, Hb, meta, rp3, filt + 6);
    epilogue_kernel<<<512, 256, 0, stream>>>(X0h, Hb, linW0, linb0, mid);

    // ---- FastGTN block 1 ----
    proj_kernel<<<1024, 256, 0, stream>>>(mid, Ws1, X0h);
    spmm_kernel<<<NN / 4, 256, 0, stream>>>(X0h, Ha, meta, rp3, filt + 12);
    spmm_kernel<<<NN / 4, 256, 0, stream>>>(Ha, Hb, meta, rp3, filt + 18);
    epilogue_kernel<<<512, 256, 0, stream>>>(X0h, Hb, linW1, linb1, out);
}

// Round 6
// 436.475 us; speedup vs baseline: 1.6370x; 1.1474x over previous
//
#include <hip/hip_runtime.h>
#include <hip/hip_fp16.h>

// Problem constants
#define NN 50000              // num nodes
#define EE 300000             // edges per type
#define ETOT (3 * EE)         // 900000
#define HD 64                 // hidden / feature size
#define SCAN_BLOCKS ((NN + 1023) / 1024)   // 49

// H layout: __half2 H[n*64+f] = (channel0, channel1), fp16 storage fp32 math
// meta[pos] = col | (etype<<16) | (q14<<18),  q14 = round(val * 16383)

// ---------------------------------------------------------------------------
// filt[b][l][c][t] = softmax(layerW_b[l][c][:])[t]   -> 24 floats
// ---------------------------------------------------------------------------
__global__ void filt_kernel(const float* __restrict__ lw0,
                            const float* __restrict__ lw1,
                            float* __restrict__ filt) {
    int i = threadIdx.x;
    if (i < 8) {
        int b = i >> 2, l = (i >> 1) & 1, c = i & 1;
        const float* lw = (b == 0 ? lw0 : lw1) + l * 6 + c * 3;
        float a0 = lw[0], a1 = lw[1], a2 = lw[2];
        float m  = fmaxf(a0, fmaxf(a1, a2));
        float e0 = expf(a0 - m), e1 = expf(a1 - m), e2 = expf(a2 - m);
        float s  = e0 + e1 + e2;
        float* o = filt + i * 3;
        o[0] = e0 / s; o[1] = e1 / s; o[2] = e2 / s;
    }
}

// ---------------------------------------------------------------------------
// CSR over row : histogram -> 3-phase scan -> scatter
// ---------------------------------------------------------------------------
__global__ void __launch_bounds__(256)
hist_kernel(const int* __restrict__ ei0, const int* __restrict__ ei1,
            const int* __restrict__ ei2, int* __restrict__ cnt) {
    int t = blockIdx.y;
    const int* ei = (t == 0) ? ei0 : (t == 1) ? ei1 : ei2;
    int e = blockIdx.x * 256 + threadIdx.x;
    if (e < EE) atomicAdd(&cnt[ei[e]], 1);
}

__global__ void __launch_bounds__(1024)
scanA_kernel(const int* __restrict__ cnt, int* __restrict__ incl,
             int* __restrict__ bsum) {
    __shared__ int wsum[16];
    int tid = threadIdx.x;
    int i = blockIdx.x * 1024 + tid;
    int lane = tid & 63, wv = tid >> 6;
    int v = (i < NN) ? cnt[i] : 0;
    int x = v;
#pragma unroll
    for (int d = 1; d < 64; d <<= 1) {
        int y = __shfl_up(x, d);
        if (lane >= d) x += y;
    }
    if (lane == 63) wsum[wv] = x;
    __syncthreads();
    if (wv == 0 && lane < 16) {
        int y = wsum[lane];
#pragma unroll
        for (int d = 1; d < 16; d <<= 1) {
            int z = __shfl_up(y, d);
            if (lane >= d) y += z;
        }
        wsum[lane] = y;
    }
    __syncthreads();
    if (wv > 0) x += wsum[wv - 1];
    if (i < NN) incl[i] = x;
    if (tid == 1023) bsum[blockIdx.x] = x;
}

__global__ void __launch_bounds__(64)
scanB_kernel(int* __restrict__ bsum) {
    int lane = threadIdx.x;
    int v = (lane < SCAN_BLOCKS) ? bsum[lane] : 0;
    int x = v;
#pragma unroll
    for (int d = 1; d < 64; d <<= 1) {
        int y = __shfl_up(x, d);
        if (lane >= d) x += y;
    }
    if (lane < SCAN_BLOCKS) bsum[lane] = x - v;   // exclusive
}

__global__ void __launch_bounds__(1024)
scanC_kernel(const int* __restrict__ cnt, const int* __restrict__ incl,
             const int* __restrict__ bsum, int* __restrict__ rp,
             int* __restrict__ cursor) {
    int i = blockIdx.x * 1024 + threadIdx.x;
    if (i < NN) {
        int total = incl[i] + bsum[blockIdx.x];
        rp[i + 1] = total;
        cursor[i] = total - cnt[i];
    }
    if (i == 0) rp[0] = 0;
}

__global__ void __launch_bounds__(256)
scatter_kernel(const int* __restrict__ ei0, const int* __restrict__ ei1,
               const int* __restrict__ ei2,
               const float* __restrict__ ev0, const float* __restrict__ ev1,
               const float* __restrict__ ev2,
               int* __restrict__ cursor, unsigned int* __restrict__ meta) {
    int t = blockIdx.y;
    const int*   ei = (t == 0) ? ei0 : (t == 1) ? ei1 : ei2;
    const float* ev = (t == 0) ? ev0 : (t == 1) ? ev1 : ev2;
    int e = blockIdx.x * 256 + threadIdx.x;
    if (e >= EE) return;
    int row = ei[e];
    int col = ei[EE + e];
    unsigned int q = (unsigned int)__float2int_rn(ev[e] * 16383.0f);
    int pos = atomicAdd(&cursor[row], 1);
    meta[pos] = (unsigned int)col | ((unsigned int)t << 16) | (q << 18);
}

// ---------------------------------------------------------------------------
// Projection: Hh[n][o] = half2( X@Ws[0], X@Ws[1] )[n][o]
// 16-node tiles; thread = (node = tid>>4 [stride-4 over wave], 4 outputs).
// Each float4 weight read serves 4 outputs and broadcasts over the wave's
// 4 nodes -> ~4x less LDS traffic than 1-node/1-output form. 8 accs/thread,
// ~40 VGPR (round-4's 24-float4 tile spilled; keep live set small).
// ---------------------------------------------------------------------------
#define PROJ_NTILE (NN / 16)   // 3125, exact
__global__ void __launch_bounds__(256)
proj_kernel(const float* __restrict__ Xin, const float* __restrict__ Ws,
            __half2* __restrict__ Hh) {
    __shared__ float Wl[2 * 64 * 64];    // 32 KB, [c][f][o]
    __shared__ float Xs[16 * 65];        // padded stride 65
    int tid = threadIdx.x;
    for (int i = tid; i < 2 * 64 * 64; i += 256) Wl[i] = Ws[i];
    int oq = (tid & 15) * 4;    // 4 consecutive outputs
    int ln = tid >> 4;          // node 0..15
    for (int tile = blockIdx.x; tile < PROJ_NTILE; tile += gridDim.x) {
        int n0 = tile * 16;
        __syncthreads();
        for (int i = tid; i < 16 * 64; i += 256)
            Xs[(i >> 6) * 65 + (i & 63)] = Xin[(n0 + (i >> 6)) * 64 + (i & 63)];
        __syncthreads();
        float a0[4] = {0.f, 0.f, 0.f, 0.f};
        float a1[4] = {0.f, 0.f, 0.f, 0.f};
        for (int f = 0; f < 64; ++f) {
            float  x  = Xs[ln * 65 + f];
            float4 w0 = *(const float4*)&Wl[f * 64 + oq];
            float4 w1 = *(const float4*)&Wl[4096 + f * 64 + oq];
            a0[0] += x * w0.x; a0[1] += x * w0.y;
            a0[2] += x * w0.z; a0[3] += x * w0.w;
            a1[0] += x * w1.x; a1[1] += x * w1.y;
            a1[2] += x * w1.z; a1[3] += x * w1.w;
        }
        float4 o4;
        ((__half2*)&o4)[0] = __floats2half2_rn(a0[0], a1[0]);
        ((__half2*)&o4)[1] = __floats2half2_rn(a0[1], a1[1]);
        ((__half2*)&o4)[2] = __floats2half2_rn(a0[2], a1[2]);
        ((__half2*)&o4)[3] = __floats2half2_rn(a0[3], a1[3]);
        *(float4*)&Hh[(n0 + ln) * HD + oq] = o4;
    }
}

// ---------------------------------------------------------------------------
// CSR SpMM-mix, wide-gather form: one wave per row. lane = (g = lane>>4
// edge-subslot, fq = lane&15 feature-quad). Per 4 edges the wave issues ONE
// global_load_dwordx4 per lane (16 B x 64 lanes = 4 x 256 B rows) instead of
// 4 dword loads. Zero-padded meta contributes 0, so loops need no tails.
// Final 4-group reduction: shfl_xor 16/32.
// ---------------------------------------------------------------------------
__global__ void __launch_bounds__(256)
spmm_kernel(const float4* __restrict__ Hin4, float4* __restrict__ Hout4,
            const unsigned int* __restrict__ meta, const int* __restrict__ rp,
            const float* __restrict__ filt /* [2][3] for this pass */) {
    const int wid  = threadIdx.x >> 6;
    const int lane = threadIdx.x & 63;
    const int g    = lane >> 4;
    const int fq   = lane & 15;
    const int row  = blockIdx.x * 4 + wid;

    const float s = 1.0f / 16383.0f;
    const float F00 = filt[0] * s, F01 = filt[1] * s, F02 = filt[2] * s;
    const float F10 = filt[3] * s, F11 = filt[4] * s, F12 = filt[5] * s;

    float accA[4] = {0.f, 0.f, 0.f, 0.f};   // ch0, features fq*4..+3
    float accB[4] = {0.f, 0.f, 0.f, 0.f};   // ch1

    const int beg = rp[row], end = rp[row + 1];
    for (int j0 = beg; j0 < end; j0 += 64) {
        int cnt = min(end - j0, 64);
        unsigned int m = (lane < cnt) ? meta[j0 + lane] : 0u;
        for (int k = 0; k < cnt; k += 8) {
            unsigned int mmA = (unsigned int)__shfl((int)m, k + g);
            unsigned int mmB = (unsigned int)__shfl((int)m, k + 4 + g);
            float4 rA = Hin4[(mmA & 0xffffu) * 16 + fq];
            float4 rB = Hin4[(mmB & 0xffffu) * 16 + fq];
            int   etA = (mmA >> 16) & 3,  etB = (mmB >> 16) & 3;
            float qA  = (float)(mmA >> 18), qB = (float)(mmB >> 18);
            float w0A = qA * ((etA == 0) ? F00 : (etA == 1) ? F01 : F02);
            float w1A = qA * ((etA == 0) ? F10 : (etA == 1) ? F11 : F12);
            float w0B = qB * ((etB == 0) ? F00 : (etB == 1) ? F01 : F02);
            float w1B = qB * ((etB == 0) ? F10 : (etB == 1) ? F11 : F12);
#pragma unroll
            for (int i = 0; i < 4; ++i) {
                float2 xA = __half22float2(((const __half2*)&rA)[i]);
                float2 xB = __half22float2(((const __half2*)&rB)[i]);
                accA[i] += w0A * xA.x + w0B * xB.x;
                accB[i] += w1A * xA.y + w1B * xB.y;
            }
        }
    }
    // reduce the 4 edge-subslot groups (lane bits 4,5)
#pragma unroll
    for (int i = 0; i < 4; ++i) {
        accA[i] += __shfl_xor(accA[i], 16); accA[i] += __shfl_xor(accA[i], 32);
        accB[i] += __shfl_xor(accB[i], 16); accB[i] += __shfl_xor(accB[i], 32);
    }
    if (g == 0) {
        float4 o4;
        ((__half2*)&o4)[0] = __floats2half2_rn(accA[0], accB[0]);
        ((__half2*)&o4)[1] = __floats2half2_rn(accA[1], accB[1]);
        ((__half2*)&o4)[2] = __floats2half2_rn(accA[2], accB[2]);
        ((__half2*)&o4)[3] = __floats2half2_rn(accA[3], accB[3]);
        Hout4[row * 16 + fq] = o4;
    }
}

// ---------------------------------------------------------------------------
// Epilogue: Hm = 0.8*relu(0.5*X0+0.5*H) + 0.2*X0 per [c][n][d], then
// out[n] = relu(Hm[n,:128] @ linW + linb).  64-node tiles, 4x4 reg tile.
// ---------------------------------------------------------------------------
#define EPI_TILE 64
#define HS_STRIDE 132   // pad: 16B-aligned rows, conflict-spread
__global__ void __launch_bounds__(256)
epilogue_kernel(const __half2* __restrict__ X0, const __half2* __restrict__ H,
                const float* __restrict__ linW, const float* __restrict__ linb,
                float* __restrict__ out) {
    __shared__ float Wl[128 * 64];               // 32 KB
    __shared__ float Hs[EPI_TILE * HS_STRIDE];   // 33.8 KB
    int tid = threadIdx.x;
    for (int i = tid; i < 128 * 64; i += 256) Wl[i] = linW[i];
    int oq = tid & 15, nq = tid >> 4;
    float bias[4];
#pragma unroll
    for (int i = 0; i < 4; ++i) bias[i] = linb[oq + 16 * i];
    const int ntiles = (NN + EPI_TILE - 1) / EPI_TILE;
    for (int tile = blockIdx.x; tile < ntiles; tile += gridDim.x) {
        int n0 = tile * EPI_TILE;
        __syncthreads();
        for (int i = tid; i < EPI_TILE * 64; i += 256) {
            int ln = i >> 6, d = i & 63;
            int n = n0 + ln;
            float2 x0 = make_float2(0.f, 0.f), h = make_float2(0.f, 0.f);
            if (n < NN) {
                x0 = __half22float2(X0[n * HD + d]);
                h  = __half22float2(H [n * HD + d]);
            }
            float z0 = fmaxf(0.5f * x0.x + 0.5f * h.x, 0.f);
            float z1 = fmaxf(0.5f * x0.y + 0.5f * h.y, 0.f);
            Hs[ln * HS_STRIDE + d]      = 0.8f * z0 + 0.2f * x0.x;
            Hs[ln * HS_STRIDE + 64 + d] = 0.8f * z1 + 0.2f * x0.y;
        }
        __syncthreads();
        float acc[4][4];
#pragma unroll
        for (int j = 0; j < 4; ++j)
#pragma unroll
            for (int i = 0; i < 4; ++i) acc[j][i] = bias[i];
        for (int k = 0; k < 128; k += 4) {
            float4 hq[4];
#pragma unroll
            for (int j = 0; j < 4; ++j)
                hq[j] = *(const float4*)&Hs[(nq + 16 * j) * HS_STRIDE + k];
#pragma unroll
            for (int kk = 0; kk < 4; ++kk) {
                float w[4];
#pragma unroll
                for (int i = 0; i < 4; ++i) w[i] = Wl[(k + kk) * 64 + oq + 16 * i];
#pragma unroll
                for (int j = 0; j < 4; ++j) {
                    float x = (kk == 0) ? hq[j].x : (kk == 1) ? hq[j].y
                             : (kk == 2) ? hq[j].z : hq[j].w;
#pragma unroll
                    for (int i = 0; i < 4; ++i) acc[j][i] += x * w[i];
                }
            }
        }
#pragma unroll
        for (int j = 0; j < 4; ++j) {
            int n = n0 + nq + 16 * j;
            if (n < NN) {
#pragma unroll
                for (int i = 0; i < 4; ++i)
                    out[n * HD + oq + 16 * i] = fmaxf(acc[j][i], 0.f);
            }
        }
    }
}

// ---------------------------------------------------------------------------
extern "C" void kernel_launch(void* const* d_in, const int* in_sizes, int n_in,
                              void* d_out, int out_size, void* d_ws, size_t ws_size,
                              hipStream_t stream) {
    const float* X     = (const float*)d_in[0];
    const float* ev0   = (const float*)d_in[1];
    const float* ev1   = (const float*)d_in[2];
    const float* ev2   = (const float*)d_in[3];
    const float* Ws0   = (const float*)d_in[4];
    const float* Ws1   = (const float*)d_in[5];
    const float* lw0   = (const float*)d_in[6];
    const float* lw1   = (const float*)d_in[7];
    const float* linW0 = (const float*)d_in[8];
    const float* linb0 = (const float*)d_in[9];
    const float* linW1 = (const float*)d_in[10];
    const float* linb1 = (const float*)d_in[11];
    const int*   ei0   = (const int*)d_in[12];
    const int*   ei1   = (const int*)d_in[13];
    const int*   ei2   = (const int*)d_in[14];
    float* out = (float*)d_out;

    // Workspace (4-byte units):
    // X0h | Ha | Hb (each NN*HD half2) | mid (NN*HD f32) | filt(32) |
    // cnt(NN) | incl(NN) | bsum(64) | rp(NN+1) | cursor(NN) | meta(ETOT)
    float* ws = (float*)d_ws;
    __half2* X0h = (__half2*)(ws);
    __half2* Ha  = (__half2*)(ws + 1 * NN * HD);
    __half2* Hb  = (__half2*)(ws + 2 * NN * HD);
    float*   mid = ws + 3 * NN * HD;
    float*   filt = ws + 4 * NN * HD;
    int*     cnt    = (int*)(filt + 32);
    int*     incl   = cnt + NN;
    int*     bsum   = incl + NN;
    int*     rp     = bsum + 64;
    int*     cursor = rp + NN + 1;
    unsigned int* meta = (unsigned int*)(cursor + NN);

    // ---- filters + row-CSR, once per launch ----
    filt_kernel<<<1, 64, 0, stream>>>(lw0, lw1, filt);
    hipMemsetAsync(cnt, 0, NN * sizeof(int), stream);
    dim3 egrid((EE + 255) / 256, 3);
    hist_kernel<<<egrid, 256, 0, stream>>>(ei0, ei1, ei2, cnt);
    scanA_kernel<<<SCAN_BLOCKS, 1024, 0, stream>>>(cnt, incl, bsum);
    scanB_kernel<<<1, 64, 0, stream>>>(bsum);
    scanC_kernel<<<SCAN_BLOCKS, 1024, 0, stream>>>(cnt, incl, bsum, rp, cursor);
    scatter_kernel<<<egrid, 256, 0, stream>>>(ei0, ei1, ei2, ev0, ev1, ev2,
                                              cursor, meta);

    // ---- FastGTN block 0 ----
    proj_kernel<<<512, 256, 0, stream>>>(X, Ws0, X0h);
    spmm_kernel<<<NN / 4, 256, 0, stream>>>((const float4*)X0h, (float4*)Ha,
                                            meta, rp, filt + 0);
    spmm_kernel<<<NN / 4, 256, 0, stream>>>((const float4*)Ha, (float4*)Hb,
                                            meta, rp, filt + 6);
    epilogue_kernel<<<512, 256, 0, stream>>>(X0h, Hb, linW0, linb0, mid);

    // ---- FastGTN block 1 ----
    proj_kernel<<<512, 256, 0, stream>>>(mid, Ws1, X0h);
    spmm_kernel<<<NN / 4, 256, 0, stream>>>((const float4*)X0h, (float4*)Ha,
                                            meta, rp, filt + 12);
    spmm_kernel<<<NN / 4, 256, 0, stream>>>((const float4*)Ha, (float4*)Hb,
                                            meta, rp, filt + 18);
    epilogue_kernel<<<512, 256, 0, stream>>>(X0h, Hb, linW1, linb1, out);
}